// Round 22
// baseline (193.421 us; speedup 1.0000x reference)
//
#include <hip/hip_runtime.h>
#include <math.h>

#define IN_F 128
#define OUT_F 32
#define HEADS 4
#define HC 128  // HEADS*OUT_F
#define NEG_SLOPE 0.2f
#define LOG2E 1.44269504088896f
#define ALD 136      // padded LDS A-row stride in bf16 (+8 breaks bank alignment)
#define HB 128       // CSR-build chunk-owner blocks (R24: halves hist matrix)
#define NBIN4 6256   // u32 nibble-bins (8 nodes/u32) covering 50048 nodes = 25 KB

typedef short bf16x8 __attribute__((ext_vector_type(8)));
typedef float f32x4 __attribute__((ext_vector_type(4)));

__device__ __forceinline__ unsigned short f2bf(float f) {  // RNE fp32->bf16
    unsigned u = __float_as_uint(f);
    u += 0x7FFFu + ((u >> 16) & 1u);
    return (unsigned short)(u >> 16);
}

// ---------------------------------------------------------------------------
// 0) prep: Wt[n][k] = bf16(concat(Wl,Wr)[k][n]) + cursor zero.
// ---------------------------------------------------------------------------
__global__ void __launch_bounds__(256)
prep_kernel(const float* __restrict__ Wl, const float* __restrict__ Wr,
            unsigned short* __restrict__ Wt, unsigned int* __restrict__ cursor) {
    const int t0 = blockIdx.x * 256 + threadIdx.x;
    const int stride = gridDim.x * 256;
    for (int i = t0; i < 256 * IN_F; i += stride) {
        const int n = i >> 7, k = i & 127;
        const float v = (n < 128) ? Wl[k * 128 + n] : Wr[k * 128 + (n - 128)];
        Wt[i] = f2bf(v);
    }
    if (t0 == 0) *cursor = 0u;
}

// ---------------------------------------------------------------------------
// 1) histproj — R24 config (verified): 512 thr; hist nibble bins / proj
//    128-row 8-wave MFMA tile; HB=128.
// ---------------------------------------------------------------------------
__global__ void __launch_bounds__(512)
histproj_kernel(const int* __restrict__ ei, unsigned char* __restrict__ hist,
                unsigned char* __restrict__ rank8,
                const float* __restrict__ x, const unsigned short* __restrict__ Wt,
                unsigned short* __restrict__ xlb, float* __restrict__ xr,
                int N, int E0, int Etot) {
    __shared__ __align__(16) unsigned char smem[128 * ALD * 2];  // 34816 B
    const int tid = threadIdx.x;

    if (blockIdx.x < HB) {
        // ---------------- hist part ----------------
        unsigned int* h = (unsigned int*)smem;
        const int b = blockIdx.x;
        const int epb = (Etot + HB - 1) / HB;
        const int t0 = b * epb, t1 = min(t0 + epb, Etot);
        for (int i = tid; i < NBIN4; i += 512) h[i] = 0u;
        __syncthreads();
        for (int t = t0 + tid; t < t1; t += 512) {
            const int dst = (t < E0) ? ei[E0 + t] : (t - E0);
            const unsigned sh = (dst & 7) * 4;
            const unsigned old = atomicAdd(&h[dst >> 3], 1u << sh);
            rank8[t] = (unsigned char)((old >> sh) & 0xFu);   // local rank <= 15
        }
        __syncthreads();
        // expand nibbles -> u8 and write as u32 words (4 nodes/word)
        unsigned int* row = (unsigned int*)&hist[(size_t)b * N];
        const int N4 = N >> 2;
        for (int i4 = tid; i4 < N4; i4 += 512) {
            unsigned w = h[i4 >> 1];
            if (i4 & 1) w >>= 16;
            row[i4] = (w & 0xFu) | ((w & 0xF0u) << 4) |
                      ((w & 0xF00u) << 8) | ((w & 0xF000u) << 12);
        }
    } else {
        // ---------------- proj part (128-row tile, 8 waves) ----------------
        unsigned short* As = (unsigned short*)smem;
        const int pb = blockIdx.x - HB;
        const int n0 = pb * 128;
#pragma unroll
        for (int q = 0; q < 8; ++q) {
            const int idx = q * 512 + tid;       // float4 index over 128x128 tile
            const int row = idx >> 5;
            const int col4 = (idx & 31) * 4;
            const float4 v = *(const float4*)&x[(size_t)min(n0 + row, N - 1) * IN_F + col4];
            ushort4 p;
            p.x = f2bf(v.x); p.y = f2bf(v.y); p.z = f2bf(v.z); p.w = f2bf(v.w);
            *(ushort4*)&As[row * ALD + col4] = p;
        }
        __syncthreads();

        const int w = tid >> 6, lane = tid & 63;
        const int lm = lane & 15, lg = lane >> 4;

        bf16x8 af[4];
#pragma unroll
        for (int kk = 0; kk < 4; ++kk)
            af[kk] = *(const bf16x8*)&As[(w * 16 + lm) * ALD + kk * 32 + lg * 8];

        f32x4 acc[16];
#pragma unroll
        for (int c = 0; c < 16; ++c) acc[c] = (f32x4){0.f, 0.f, 0.f, 0.f};

#pragma unroll
        for (int c = 0; c < 16; ++c) {
#pragma unroll
            for (int kk = 0; kk < 4; ++kk) {
                const bf16x8 bf = *(const bf16x8*)&Wt[(size_t)(c * 16 + lm) * 128 + kk * 32 + lg * 8];
                acc[c] = __builtin_amdgcn_mfma_f32_16x16x32_bf16(af[kk], bf, acc[c], 0, 0, 0);
            }
        }

        const int rbase = n0 + w * 16 + lg * 4;
#pragma unroll
        for (int c = 0; c < 16; ++c) {
#pragma unroll
            for (int r = 0; r < 4; ++r) {
                const int R = rbase + r;
                if (R >= N) continue;
                const int C = c * 16 + lm;
                if (c < 8) xlb[(size_t)R * HC + C] = f2bf(acc[c][r]);
                else       xr[(size_t)R * HC + (C - 128)] = acc[c][r];
            }
        }
    }
}

// ---------------------------------------------------------------------------
// 2) reduce+alloc — R24 (verified): 4 segs x 32 rows (HB=128).
// ---------------------------------------------------------------------------
__global__ void __launch_bounds__(256)
reduce_alloc_kernel(unsigned int* __restrict__ hist32, int* __restrict__ deg,
                    int* __restrict__ start, unsigned int* __restrict__ cursor,
                    int N4) {
    __shared__ unsigned int segp[4][64];
    __shared__ int sc[64];
    __shared__ int base_s;
    const int tid = threadIdx.x;
    const int q = tid & 63, s = tid >> 6;
    const int n4 = blockIdx.x * 64 + q;
    const int R = HB / 4;   // rows per segment

    unsigned psum = 0u;
    if (n4 < N4) {
#pragma unroll 8
        for (int bb = s * R; bb < s * R + R; ++bb)
            psum += hist32[(size_t)bb * N4 + n4];
    }
    segp[s][q] = psum;
    __syncthreads();

    unsigned rebase = 0u;
    for (int s2 = 0; s2 < s; ++s2) rebase += segp[s2][q];

    if (n4 < N4) {
        unsigned run = rebase;
#pragma unroll 8
        for (int bb = s * R; bb < s * R + R; ++bb) {
            const size_t idx = (size_t)bb * N4 + n4;
            const unsigned w = hist32[idx];
            hist32[idx] = run;
            run += w;
        }
    }

    const unsigned totp = segp[0][q] + segp[1][q] + segp[2][q] + segp[3][q];
    const int d0 = totp & 0xFF, d1 = (totp >> 8) & 0xFF,
              d2 = (totp >> 16) & 0xFF, d3 = (int)(totp >> 24);
    const int tot = d0 + d1 + d2 + d3;

    if (s == 0) sc[q] = (n4 < N4) ? tot : 0;
    __syncthreads();
#pragma unroll
    for (int off = 1; off < 64; off <<= 1) {
        int v = (s == 0 && q >= off) ? sc[q - off] : 0;
        __syncthreads();
        if (s == 0) sc[q] += v;
        __syncthreads();
    }
    if (tid == 63) base_s = (int)atomicAdd(cursor, (unsigned int)sc[63]);
    __syncthreads();
    if (s == 0 && n4 < N4) {
        const int e = base_s + sc[q] - tot;   // exclusive start of node 4*n4
        int4 st, dg;
        st.x = e; st.y = e + d0; st.z = st.y + d1; st.w = st.z + d2;
        dg.x = d0; dg.y = d1; dg.z = d2; dg.w = d3;
        *(int4*)&start[n4 * 4] = st;
        *(int4*)&deg[n4 * 4] = dg;
    }
}

// ---------------------------------------------------------------------------
// 3) scatter — R18 (verified): pure streaming, NO LDS.
// ---------------------------------------------------------------------------
__global__ void __launch_bounds__(512)
scatter2_kernel(const int* __restrict__ ei, const int* __restrict__ start,
                const unsigned char* __restrict__ hist,
                const unsigned char* __restrict__ rank8,
                int* __restrict__ esrc, int N, int E0, int Etot) {
    const int b = blockIdx.x;
    const int epb = (Etot + HB - 1) / HB;
    const int t0 = b * epb, t1 = min(t0 + epb, Etot);
    const unsigned char* hrow = &hist[(size_t)b * N];
    for (int t = t0 + threadIdx.x; t < t1; t += 512) {
        int src, dst;
        if (t < E0) { src = ei[t]; dst = ei[E0 + t]; }
        else        { src = dst = t - E0; }
        esrc[start[dst] + (int)hrow[dst] + (int)rank8[t]] = src;
    }
}

// ---------------------------------------------------------------------------
// 4) Fused attention + softmax + aggregation.
//    R25: prefetch clamp 63 -> cnt-1.  With d~17, clamp-63 made garbage
//    prefetch lanes gather DISTINCT random 256B lines (~40% wasted fetch,
//    FETCH 103.6MB vs ~70 ideal).  Clamp to cnt-1 makes them re-read the
//    last valid edge's line — L1-hot, near-free.  Rest byte-unchanged.
// ---------------------------------------------------------------------------
template <int CTRL>
__device__ __forceinline__ float dpp_add(float v) {
    const int t = __builtin_amdgcn_update_dpp(
        0, __float_as_int(v), CTRL, 0xF, 0xF, true);
    return v + __int_as_float(t);
}

__device__ __forceinline__ float row_sum_bcast(float c) {
    c = dpp_add<0xB1>(c);   // quad_perm [1,0,3,2]  (xor 1)
    c = dpp_add<0x4E>(c);   // quad_perm [2,3,0,1]  (xor 2)
    c = dpp_add<0x124>(c);  // row_ror:4
    c = dpp_add<0x128>(c);  // row_ror:8 -> every lane holds 16-lane sum
    return c;
}

__global__ void __launch_bounds__(256)
fused_agg_kernel(const unsigned short* __restrict__ xlb,
                 const float* __restrict__ xr,
                 const float* __restrict__ att,
                 const float* __restrict__ bias,
                 const int* __restrict__ esrc,
                 const int* __restrict__ start,
                 const int* __restrict__ deg,
                 float* __restrict__ out, int N, int EtotM1) {
    const int wid = threadIdx.x >> 6;
    const int lane = threadIdx.x & 63;
    const int n = blockIdx.x * 4 + wid;
    if (n >= N) return;

    const int ch = lane * 2;  // channel pair; head = lane>>4 = DPP row
    const float2 xr2 = *(const float2*)&xr[(size_t)n * HC + ch];
    const float2 at2 = *(const float2*)&att[ch];
    const float au0 = at2.x * LOG2E, au1 = at2.y * LOG2E;
    const int s0 = start[n];
    const int d = deg[n];                      // >= 1 (self-loop)

    float sum = 0.f, ax = 0.f, ay = 0.f;

    auto body = [&](unsigned pk) {
        const float vx = __uint_as_float(pk << 16);
        const float vy = __uint_as_float(pk & 0xFFFF0000u);
        const float sx = vx + xr2.x;
        const float sy = vy + xr2.y;
        const float lx = fmaxf(sx, sx * NEG_SLOPE);
        const float ly = fmaxf(sy, sy * NEG_SLOPE);
        const float c = fmaf(au1, ly, au0 * lx);
        const float p = __builtin_amdgcn_exp2f(row_sum_bcast(c));
        sum += p;
        ax = fmaf(p, vx, ax);
        ay = fmaf(p, vy, ay);
    };

    for (int jb = 0; jb < d; jb += 64) {
        const int cnt = min(64, d - jb);
        const int cm1 = cnt - 1;
        const int ev = esrc[min(s0 + jb + lane, EtotM1)];

#define LDE(i) (*(const unsigned*)&xlb[(size_t)__builtin_amdgcn_readlane(ev, (i)) * HC + ch])
        unsigned pk0 = LDE(0),            pk1 = LDE(min(1, cm1)),
                 pk2 = LDE(min(2, cm1)),  pk3 = LDE(min(3, cm1)),
                 pk4 = LDE(min(4, cm1)),  pk5 = LDE(min(5, cm1)),
                 pk6 = LDE(min(6, cm1)),  pk7 = LDE(min(7, cm1));

        int j = 0;
        for (; j + 7 < cnt; j += 8) {
            const unsigned q0 = LDE(min(j + 8, cm1));
            const unsigned q1 = LDE(min(j + 9, cm1));
            const unsigned q2 = LDE(min(j + 10, cm1));
            const unsigned q3 = LDE(min(j + 11, cm1));
            const unsigned q4 = LDE(min(j + 12, cm1));
            const unsigned q5 = LDE(min(j + 13, cm1));
            const unsigned q6 = LDE(min(j + 14, cm1));
            const unsigned q7 = LDE(min(j + 15, cm1));
            body(pk0); body(pk1); body(pk2); body(pk3);
            body(pk4); body(pk5); body(pk6); body(pk7);
            pk0 = q0; pk1 = q1; pk2 = q2; pk3 = q3;
            pk4 = q4; pk5 = q5; pk6 = q6; pk7 = q7;
        }
        for (; j < cnt; ++j) {  // 0..7 tail edges
            body(pk0);
            pk0 = pk1; pk1 = pk2; pk2 = pk3; pk3 = pk4;
            pk4 = pk5; pk5 = pk6; pk6 = pk7;
        }
#undef LDE
    }
    const float inv = __builtin_amdgcn_rcpf(sum + 1e-16f);
    const float2 b2 = *(const float2*)&bias[ch];
    float2 o;
    o.x = fmaf(ax, inv, b2.x);
    o.y = fmaf(ay, inv, b2.y);
    *(float2*)&out[(size_t)n * HC + ch] = o;
}

// ---------------------------------------------------------------------------
extern "C" void kernel_launch(void* const* d_in, const int* in_sizes, int n_in,
                              void* d_out, int out_size, void* d_ws, size_t ws_size,
                              hipStream_t stream) {
    const float* x    = (const float*)d_in[0];
    const int*   ei   = (const int*)d_in[1];   // harness delivers int inputs as int32
    const float* Wl   = (const float*)d_in[2];
    const float* Wr   = (const float*)d_in[3];
    const float* att  = (const float*)d_in[4];
    const float* bias = (const float*)d_in[5];
    float* out        = (float*)d_out;

    const int N    = in_sizes[0] / IN_F;   // 50000
    const int E0   = in_sizes[1] / 2;      // 800000
    const int Etot = E0 + N;               // 850000

    char* base = (char*)d_ws;
    unsigned short* xlb = (unsigned short*)base; base += (size_t)N * HC * sizeof(unsigned short);
    float* xr   = (float*)base;        base += (size_t)N * HC * sizeof(float);
    int*   esrc = (int*)base;          base += (size_t)Etot * sizeof(int);
    int*   strt = (int*)base;          base += (size_t)N * sizeof(int);
    int*   deg  = (int*)base;          base += (size_t)N * sizeof(int);
    unsigned char* hist = (unsigned char*)base; base += (size_t)HB * N * sizeof(unsigned char);
    unsigned char* rank8 = (unsigned char*)base; base += (size_t)Etot * sizeof(unsigned char);
    // Etot = 850000 (mult of 4) -> Wt stays 4B-aligned
    unsigned short* Wt = (unsigned short*)base; base += 256 * IN_F * sizeof(unsigned short);
    unsigned int* cursor = (unsigned int*)base;

    const int projB = (N + 127) / 128;   // 391
    prep_kernel<<<128, 256, 0, stream>>>(Wl, Wr, Wt, cursor);
    histproj_kernel<<<HB + projB, 512, 0, stream>>>(ei, hist, rank8, x, Wt,
                                                    xlb, xr, N, E0, Etot);
    reduce_alloc_kernel<<<(N / 4 + 63) / 64, 256, 0, stream>>>(
        (unsigned int*)hist, deg, strt, cursor, N / 4);
    scatter2_kernel<<<HB, 512, 0, stream>>>(ei, strt, hist, rank8, esrc,
                                            N, E0, Etot);
    fused_agg_kernel<<<(N + 3) / 4, 256, 0, stream>>>(xlb, xr, att, bias, esrc, strt, deg,
                                                      out, N, Etot - 1);
}

// Round 23
// 191.124 us; speedup vs baseline: 1.0120x; 1.0120x over previous
//
#include <hip/hip_runtime.h>
#include <math.h>

#define IN_F 128
#define OUT_F 32
#define HEADS 4
#define HC 128  // HEADS*OUT_F
#define NEG_SLOPE 0.2f
#define LOG2E 1.44269504088896f
#define ALD 136      // padded LDS A-row stride in bf16 (+8 breaks bank alignment)
#define HB 128       // CSR-build chunk-owner blocks (R24: halves hist matrix)
#define NBIN4 6256   // u32 nibble-bins (8 nodes/u32) covering 50048 nodes = 25 KB

typedef short bf16x8 __attribute__((ext_vector_type(8)));
typedef float f32x4 __attribute__((ext_vector_type(4)));

__device__ __forceinline__ unsigned short f2bf(float f) {  // RNE fp32->bf16
    unsigned u = __float_as_uint(f);
    u += 0x7FFFu + ((u >> 16) & 1u);
    return (unsigned short)(u >> 16);
}

// ---------------------------------------------------------------------------
// 0) prep: Wt[n][k] = bf16(concat(Wl,Wr)[k][n]) + cursor zero.
// ---------------------------------------------------------------------------
__global__ void __launch_bounds__(256)
prep_kernel(const float* __restrict__ Wl, const float* __restrict__ Wr,
            unsigned short* __restrict__ Wt, unsigned int* __restrict__ cursor) {
    const int t0 = blockIdx.x * 256 + threadIdx.x;
    const int stride = gridDim.x * 256;
    for (int i = t0; i < 256 * IN_F; i += stride) {
        const int n = i >> 7, k = i & 127;
        const float v = (n < 128) ? Wl[k * 128 + n] : Wr[k * 128 + (n - 128)];
        Wt[i] = f2bf(v);
    }
    if (t0 == 0) *cursor = 0u;
}

// ---------------------------------------------------------------------------
// 1) histproj — R24 config (verified): 512 thr; hist nibble bins / proj
//    128-row 8-wave MFMA tile; HB=128.
// ---------------------------------------------------------------------------
__global__ void __launch_bounds__(512)
histproj_kernel(const int* __restrict__ ei, unsigned char* __restrict__ hist,
                unsigned char* __restrict__ rank8,
                const float* __restrict__ x, const unsigned short* __restrict__ Wt,
                unsigned short* __restrict__ xlb, float* __restrict__ xr,
                int N, int E0, int Etot) {
    __shared__ __align__(16) unsigned char smem[128 * ALD * 2];  // 34816 B
    const int tid = threadIdx.x;

    if (blockIdx.x < HB) {
        // ---------------- hist part ----------------
        unsigned int* h = (unsigned int*)smem;
        const int b = blockIdx.x;
        const int epb = (Etot + HB - 1) / HB;
        const int t0 = b * epb, t1 = min(t0 + epb, Etot);
        for (int i = tid; i < NBIN4; i += 512) h[i] = 0u;
        __syncthreads();
        for (int t = t0 + tid; t < t1; t += 512) {
            const int dst = (t < E0) ? ei[E0 + t] : (t - E0);
            const unsigned sh = (dst & 7) * 4;
            const unsigned old = atomicAdd(&h[dst >> 3], 1u << sh);
            rank8[t] = (unsigned char)((old >> sh) & 0xFu);   // local rank <= 15
        }
        __syncthreads();
        // expand nibbles -> u8 and write as u32 words (4 nodes/word)
        unsigned int* row = (unsigned int*)&hist[(size_t)b * N];
        const int N4 = N >> 2;
        for (int i4 = tid; i4 < N4; i4 += 512) {
            unsigned w = h[i4 >> 1];
            if (i4 & 1) w >>= 16;
            row[i4] = (w & 0xFu) | ((w & 0xF0u) << 4) |
                      ((w & 0xF00u) << 8) | ((w & 0xF000u) << 12);
        }
    } else {
        // ---------------- proj part (128-row tile, 8 waves) ----------------
        unsigned short* As = (unsigned short*)smem;
        const int pb = blockIdx.x - HB;
        const int n0 = pb * 128;
#pragma unroll
        for (int q = 0; q < 8; ++q) {
            const int idx = q * 512 + tid;       // float4 index over 128x128 tile
            const int row = idx >> 5;
            const int col4 = (idx & 31) * 4;
            const float4 v = *(const float4*)&x[(size_t)min(n0 + row, N - 1) * IN_F + col4];
            ushort4 p;
            p.x = f2bf(v.x); p.y = f2bf(v.y); p.z = f2bf(v.z); p.w = f2bf(v.w);
            *(ushort4*)&As[row * ALD + col4] = p;
        }
        __syncthreads();

        const int w = tid >> 6, lane = tid & 63;
        const int lm = lane & 15, lg = lane >> 4;

        bf16x8 af[4];
#pragma unroll
        for (int kk = 0; kk < 4; ++kk)
            af[kk] = *(const bf16x8*)&As[(w * 16 + lm) * ALD + kk * 32 + lg * 8];

        f32x4 acc[16];
#pragma unroll
        for (int c = 0; c < 16; ++c) acc[c] = (f32x4){0.f, 0.f, 0.f, 0.f};

#pragma unroll
        for (int c = 0; c < 16; ++c) {
#pragma unroll
            for (int kk = 0; kk < 4; ++kk) {
                const bf16x8 bf = *(const bf16x8*)&Wt[(size_t)(c * 16 + lm) * 128 + kk * 32 + lg * 8];
                acc[c] = __builtin_amdgcn_mfma_f32_16x16x32_bf16(af[kk], bf, acc[c], 0, 0, 0);
            }
        }

        const int rbase = n0 + w * 16 + lg * 4;
#pragma unroll
        for (int c = 0; c < 16; ++c) {
#pragma unroll
            for (int r = 0; r < 4; ++r) {
                const int R = rbase + r;
                if (R >= N) continue;
                const int C = c * 16 + lm;
                if (c < 8) xlb[(size_t)R * HC + C] = f2bf(acc[c][r]);
                else       xr[(size_t)R * HC + (C - 128)] = acc[c][r];
            }
        }
    }
}

// ---------------------------------------------------------------------------
// 2) reduce+alloc — R24 (verified): 4 segs x 32 rows (HB=128).
// ---------------------------------------------------------------------------
__global__ void __launch_bounds__(256)
reduce_alloc_kernel(unsigned int* __restrict__ hist32, int* __restrict__ deg,
                    int* __restrict__ start, unsigned int* __restrict__ cursor,
                    int N4) {
    __shared__ unsigned int segp[4][64];
    __shared__ int sc[64];
    __shared__ int base_s;
    const int tid = threadIdx.x;
    const int q = tid & 63, s = tid >> 6;
    const int n4 = blockIdx.x * 64 + q;
    const int R = HB / 4;   // rows per segment

    unsigned psum = 0u;
    if (n4 < N4) {
#pragma unroll 8
        for (int bb = s * R; bb < s * R + R; ++bb)
            psum += hist32[(size_t)bb * N4 + n4];
    }
    segp[s][q] = psum;
    __syncthreads();

    unsigned rebase = 0u;
    for (int s2 = 0; s2 < s; ++s2) rebase += segp[s2][q];

    if (n4 < N4) {
        unsigned run = rebase;
#pragma unroll 8
        for (int bb = s * R; bb < s * R + R; ++bb) {
            const size_t idx = (size_t)bb * N4 + n4;
            const unsigned w = hist32[idx];
            hist32[idx] = run;
            run += w;
        }
    }

    const unsigned totp = segp[0][q] + segp[1][q] + segp[2][q] + segp[3][q];
    const int d0 = totp & 0xFF, d1 = (totp >> 8) & 0xFF,
              d2 = (totp >> 16) & 0xFF, d3 = (int)(totp >> 24);
    const int tot = d0 + d1 + d2 + d3;

    if (s == 0) sc[q] = (n4 < N4) ? tot : 0;
    __syncthreads();
#pragma unroll
    for (int off = 1; off < 64; off <<= 1) {
        int v = (s == 0 && q >= off) ? sc[q - off] : 0;
        __syncthreads();
        if (s == 0) sc[q] += v;
        __syncthreads();
    }
    if (tid == 63) base_s = (int)atomicAdd(cursor, (unsigned int)sc[63]);
    __syncthreads();
    if (s == 0 && n4 < N4) {
        const int e = base_s + sc[q] - tot;   // exclusive start of node 4*n4
        int4 st, dg;
        st.x = e; st.y = e + d0; st.z = st.y + d1; st.w = st.z + d2;
        dg.x = d0; dg.y = d1; dg.z = d2; dg.w = d3;
        *(int4*)&start[n4 * 4] = st;
        *(int4*)&deg[n4 * 4] = dg;
    }
}

// ---------------------------------------------------------------------------
// 3) scatter — R18 (verified): pure streaming, NO LDS.
// ---------------------------------------------------------------------------
__global__ void __launch_bounds__(512)
scatter2_kernel(const int* __restrict__ ei, const int* __restrict__ start,
                const unsigned char* __restrict__ hist,
                const unsigned char* __restrict__ rank8,
                int* __restrict__ esrc, int N, int E0, int Etot) {
    const int b = blockIdx.x;
    const int epb = (Etot + HB - 1) / HB;
    const int t0 = b * epb, t1 = min(t0 + epb, Etot);
    const unsigned char* hrow = &hist[(size_t)b * N];
    for (int t = t0 + threadIdx.x; t < t1; t += 512) {
        int src, dst;
        if (t < E0) { src = ei[t]; dst = ei[E0 + t]; }
        else        { src = dst = t - E0; }
        esrc[start[dst] + (int)hrow[dst] + (int)rank8[t]] = src;
    }
}

// ---------------------------------------------------------------------------
// 4) Fused attention + softmax + aggregation — R26: REVERT to the verified
//    clamp-63 R20/R24 version (43.4us).  R25's clamp-to-cnt-1 was an A/B'd
//    regression (+4us): the min(i,cm1) scalar ops cost more than the
//    single L1-hot wasted line they saved (all clamp-63 slots read lane
//    63's edge — the SAME line, not distinct random lines).
// ---------------------------------------------------------------------------
template <int CTRL>
__device__ __forceinline__ float dpp_add(float v) {
    const int t = __builtin_amdgcn_update_dpp(
        0, __float_as_int(v), CTRL, 0xF, 0xF, true);
    return v + __int_as_float(t);
}

__device__ __forceinline__ float row_sum_bcast(float c) {
    c = dpp_add<0xB1>(c);   // quad_perm [1,0,3,2]  (xor 1)
    c = dpp_add<0x4E>(c);   // quad_perm [2,3,0,1]  (xor 2)
    c = dpp_add<0x124>(c);  // row_ror:4
    c = dpp_add<0x128>(c);  // row_ror:8 -> every lane holds 16-lane sum
    return c;
}

__global__ void __launch_bounds__(256)
fused_agg_kernel(const unsigned short* __restrict__ xlb,
                 const float* __restrict__ xr,
                 const float* __restrict__ att,
                 const float* __restrict__ bias,
                 const int* __restrict__ esrc,
                 const int* __restrict__ start,
                 const int* __restrict__ deg,
                 float* __restrict__ out, int N, int EtotM1) {
    const int wid = threadIdx.x >> 6;
    const int lane = threadIdx.x & 63;
    const int n = blockIdx.x * 4 + wid;
    if (n >= N) return;

    const int ch = lane * 2;  // channel pair; head = lane>>4 = DPP row
    const float2 xr2 = *(const float2*)&xr[(size_t)n * HC + ch];
    const float2 at2 = *(const float2*)&att[ch];
    const float au0 = at2.x * LOG2E, au1 = at2.y * LOG2E;
    const int s0 = start[n];
    const int d = deg[n];                      // >= 1 (self-loop)

    float sum = 0.f, ax = 0.f, ay = 0.f;

    auto body = [&](unsigned pk) {
        const float vx = __uint_as_float(pk << 16);
        const float vy = __uint_as_float(pk & 0xFFFF0000u);
        const float sx = vx + xr2.x;
        const float sy = vy + xr2.y;
        const float lx = fmaxf(sx, sx * NEG_SLOPE);
        const float ly = fmaxf(sy, sy * NEG_SLOPE);
        const float c = fmaf(au1, ly, au0 * lx);
        const float p = __builtin_amdgcn_exp2f(row_sum_bcast(c));
        sum += p;
        ax = fmaf(p, vx, ax);
        ay = fmaf(p, vy, ay);
    };

    for (int jb = 0; jb < d; jb += 64) {
        const int cnt = min(64, d - jb);
        const int ev = esrc[min(s0 + jb + lane, EtotM1)];

#define LDE(i) (*(const unsigned*)&xlb[(size_t)__builtin_amdgcn_readlane(ev, (i)) * HC + ch])
        unsigned pk0 = LDE(0), pk1 = LDE(1), pk2 = LDE(2), pk3 = LDE(3);
        unsigned pk4 = LDE(4), pk5 = LDE(5), pk6 = LDE(6), pk7 = LDE(7);

        int j = 0;
        for (; j + 7 < cnt; j += 8) {
            const unsigned q0 = LDE(min(j + 8, 63));
            const unsigned q1 = LDE(min(j + 9, 63));
            const unsigned q2 = LDE(min(j + 10, 63));
            const unsigned q3 = LDE(min(j + 11, 63));
            const unsigned q4 = LDE(min(j + 12, 63));
            const unsigned q5 = LDE(min(j + 13, 63));
            const unsigned q6 = LDE(min(j + 14, 63));
            const unsigned q7 = LDE(min(j + 15, 63));
            body(pk0); body(pk1); body(pk2); body(pk3);
            body(pk4); body(pk5); body(pk6); body(pk7);
            pk0 = q0; pk1 = q1; pk2 = q2; pk3 = q3;
            pk4 = q4; pk5 = q5; pk6 = q6; pk7 = q7;
        }
        for (; j < cnt; ++j) {  // 0..7 tail edges
            body(pk0);
            pk0 = pk1; pk1 = pk2; pk2 = pk3; pk3 = pk4;
            pk4 = pk5; pk5 = pk6; pk6 = pk7;
        }
#undef LDE
    }
    const float inv = __builtin_amdgcn_rcpf(sum + 1e-16f);
    const float2 b2 = *(const float2*)&bias[ch];
    float2 o;
    o.x = fmaf(ax, inv, b2.x);
    o.y = fmaf(ay, inv, b2.y);
    *(float2*)&out[(size_t)n * HC + ch] = o;
}

// ---------------------------------------------------------------------------
extern "C" void kernel_launch(void* const* d_in, const int* in_sizes, int n_in,
                              void* d_out, int out_size, void* d_ws, size_t ws_size,
                              hipStream_t stream) {
    const float* x    = (const float*)d_in[0];
    const int*   ei   = (const int*)d_in[1];   // harness delivers int inputs as int32
    const float* Wl   = (const float*)d_in[2];
    const float* Wr   = (const float*)d_in[3];
    const float* att  = (const float*)d_in[4];
    const float* bias = (const float*)d_in[5];
    float* out        = (float*)d_out;

    const int N    = in_sizes[0] / IN_F;   // 50000
    const int E0   = in_sizes[1] / 2;      // 800000
    const int Etot = E0 + N;               // 850000

    char* base = (char*)d_ws;
    unsigned short* xlb = (unsigned short*)base; base += (size_t)N * HC * sizeof(unsigned short);
    float* xr   = (float*)base;        base += (size_t)N * HC * sizeof(float);
    int*   esrc = (int*)base;          base += (size_t)Etot * sizeof(int);
    int*   strt = (int*)base;          base += (size_t)N * sizeof(int);
    int*   deg  = (int*)base;          base += (size_t)N * sizeof(int);
    unsigned char* hist = (unsigned char*)base; base += (size_t)HB * N * sizeof(unsigned char);
    unsigned char* rank8 = (unsigned char*)base; base += (size_t)Etot * sizeof(unsigned char);
    // Etot = 850000 (mult of 4) -> Wt stays 4B-aligned
    unsigned short* Wt = (unsigned short*)base; base += 256 * IN_F * sizeof(unsigned short);
    unsigned int* cursor = (unsigned int*)base;

    const int projB = (N + 127) / 128;   // 391
    prep_kernel<<<128, 256, 0, stream>>>(Wl, Wr, Wt, cursor);
    histproj_kernel<<<HB + projB, 512, 0, stream>>>(ei, hist, rank8, x, Wt,
                                                    xlb, xr, N, E0, Etot);
    reduce_alloc_kernel<<<(N / 4 + 63) / 64, 256, 0, stream>>>(
        (unsigned int*)hist, deg, strt, cursor, N / 4);
    scatter2_kernel<<<HB, 512, 0, stream>>>(ei, strt, hist, rank8, esrc,
                                            N, E0, Etot);
    fused_agg_kernel<<<(N + 3) / 4, 256, 0, stream>>>(xlb, xr, att, bias, esrc, strt, deg,
                                                      out, N, Etot - 1);
}